// Round 8
// baseline (5353.548 us; speedup 1.0000x reference)
//
#include <hip/hip_runtime.h>

// VectorQuantizer: B=32768, K=8192, D=256, fp32.
// out layout (flat float): z_q [B*D], vq_loss [1], commit [1], indices-as-float [B]
// ws layout: idx_i int[B] | s_z float[B] | partial float[B/4]
//
// Numerics (verified round 2): ref dist = fl32(S - 2*fl32(dot)), dot = single
// fp32 FMA chain ascending in d per (row,code); ties (frequent — dist is
// quantized at ulp(||z||^2~256) = 3e-5) resolved by FIRST index.
// fmaf(-2,acc,S) == fl(S - 2*dot) exactly.
//
// Round-8: rounds 3-7 all ran at 12% occupancy = ONE 4-wave block per CU
// (2x80KB LDS never co-resided; "2 blocks/CU" assumption was wrong) -> every
// LDS wait fully exposed (VALUBusy 55-70%). Fix: 8 waves from ONE block.
//   512 threads (8 waves), BM=64, BN=1024, BK=4. tx=tid&63, ty=tid>>6.
//   Tile 8 rows x 16 codes/thread (acc=128). LDS: zT 64KB + eT 32KB = 96KB
//   -> 1 block/CU, 8 waves/CU = 2 waves/SIMD. VGPR ~210 <= 256 cap (512,1).
//   Per dd per CU: LDS ~480cyc (2 bcast za + 4 dense eb b128 x 8 waves) vs
//   VALU 512cyc -> VALU-bound with a partner wave to hide LDS latency.
//   Operand dbuf (za/eb ping-pong) kept from round 7.

namespace {
constexpr int NB = 32768;
constexpr int NK = 8192;
constexpr int ND = 256;
constexpr int BM = 64;    // rows per block
constexpr int BN = 1024;  // codes per chunk
constexpr int BK = 4;     // d per stage
constexpr int NT = 512;   // threads per block

// ---- S[row] = ||z_row||^2 ----
__global__ void sz_kernel(const float* __restrict__ z, float* __restrict__ sz) {
  const int row = blockIdx.x * 4 + (threadIdx.x >> 6);
  const int lane = threadIdx.x & 63;
  const float4 v = reinterpret_cast<const float4*>(z)[(size_t)row * (ND / 4) + lane];
  float s = v.x * v.x + v.y * v.y + v.z * v.z + v.w * v.w;
#pragma unroll
  for (int off = 32; off; off >>= 1) s += __shfl_down(s, off, 64);
  if (lane == 0) sz[row] = s;
}

// ---- argmin over codes of fl32(S - 2*fl32(z.e)), first-index tie-break ----
__global__ __launch_bounds__(NT, 1) void argmin_kernel(
    const float* __restrict__ z, const float* __restrict__ emb,
    const float* __restrict__ sz, int* __restrict__ idx_i,
    float* __restrict__ idx_f) {
  __shared__ float zT[ND][BM];       // 64 KB, persistent z^T tile
  __shared__ float eT[2][BK][BN];    // 32 KB, double-buffered e^T chunk

  const int tid = threadIdx.x;
  const int tx = tid & 63;   // code lane (full wave)
  const int ty = tid >> 6;   // wave id = row group (0..7), wave-uniform
  const int ty8 = ty * 8;
  const int row0 = blockIdx.x * BM;

  // stage zT (transpose z[row][d] -> zT[d][row]); coalesced, one-time
  {
    const float4* z4 = reinterpret_cast<const float4*>(z) + (size_t)row0 * (ND / 4);
#pragma unroll
    for (int it = 0; it < 8; ++it) {
      int fi = it * NT + tid;  // float4 index in tile (64 rows * 64 f4/row)
      int r = fi >> 6;
      int dq = fi & 63;
      float4 v = z4[(size_t)r * (ND / 4) + dq];
      zT[dq * 4 + 0][r] = v.x;
      zT[dq * 4 + 1][r] = v.y;
      zT[dq * 4 + 2][r] = v.z;
      zT[dq * 4 + 3][r] = v.w;
    }
  }
  __syncthreads();  // zT visible before the pipelined za prefetch below

  float best[8];
  int bidx[8];
#pragma unroll
  for (int i = 0; i < 8; ++i) { best[i] = 3.4e38f; bidx[i] = 0; }

  const float4* e4 = reinterpret_cast<const float4*>(emb);
  const int cA = tid;        // stages code rows tid and tid+512
  const int cB = tid + 512;

  float za[2][8], eb[2][16];

  auto lza = [&](int b, int d) {
    const float4 a0 = *reinterpret_cast<const float4*>(&zT[d][ty8]);
    const float4 a1 = *reinterpret_cast<const float4*>(&zT[d][ty8 + 4]);
    za[b][0] = a0.x; za[b][1] = a0.y; za[b][2] = a0.z; za[b][3] = a0.w;
    za[b][4] = a1.x; za[b][5] = a1.y; za[b][6] = a1.z; za[b][7] = a1.w;
  };
  auto leb = [&](int b, int buf, int dd) {
#pragma unroll
    for (int m = 0; m < 4; ++m) {
      const float4 e =
          *reinterpret_cast<const float4*>(&eT[buf][dd][m * 256 + tx * 4]);
      eb[b][m * 4 + 0] = e.x;
      eb[b][m * 4 + 1] = e.y;
      eb[b][m * 4 + 2] = e.z;
      eb[b][m * 4 + 3] = e.w;
    }
  };

  lza(0, 0);  // prime za pipeline (d restarts at 0 every chunk)

  for (int n = 0; n < NK / BN; ++n) {  // 8 chunks
    const int c0 = n * BN;
    float acc[8][16];
#pragma unroll
    for (int i = 0; i < 8; ++i)
#pragma unroll
      for (int j = 0; j < 16; ++j) acc[i][j] = 0.f;

    // preload dk=0 slice (1 float4 per staged code row)
    float4 p0 = e4[(size_t)(c0 + cA) * (ND / 4) + 0];
    float4 p1 = e4[(size_t)(c0 + cB) * (ND / 4) + 0];

    for (int dk = 0; dk < ND / BK; ++dk) {  // 64 stages
      const int buf = dk & 1;
      // transposed store: eT[dd][code]; lane-consecutive -> conflict-free
      eT[buf][0][cA] = p0.x;
      eT[buf][1][cA] = p0.y;
      eT[buf][2][cA] = p0.z;
      eT[buf][3][cA] = p0.w;
      eT[buf][0][cB] = p1.x;
      eT[buf][1][cB] = p1.y;
      eT[buf][2][cB] = p1.z;
      eT[buf][3][cB] = p1.w;
      if (dk + 1 < ND / BK) {  // prefetch next slice (L2/L3-served)
        p0 = e4[(size_t)(c0 + cA) * (ND / 4) + dk + 1];
        p1 = e4[(size_t)(c0 + cB) * (ND / 4) + dk + 1];
      }
      __syncthreads();  // dbuf: single barrier per stage
      leb(0, buf, 0);   // za[0] already holds d = dk*4 (rolled pipeline)
#pragma unroll
      for (int dd = 0; dd < BK; ++dd) {
        const int cur = dd & 1;
        const int nxt = cur ^ 1;
        if (dd < BK - 1) {        // prefetch next dd's operands
          lza(nxt, dk * BK + dd + 1);
          leb(nxt, buf, dd + 1);
        } else {                  // roll za into next dk (or next chunk's d=0)
          lza(nxt, (dk + 1 < ND / BK) ? (dk + 1) * BK : 0);
        }
        // single fp32 FMA chain per (row, code), ascending d
#pragma unroll
        for (int i = 0; i < 8; ++i)
#pragma unroll
          for (int j = 0; j < 16; ++j)
            acc[i][j] = fmaf(za[cur][i], eb[cur][j], acc[i][j]);
      }
    }

    // running argmin: dist = fl32(S - 2*fl32(dot)); ascending code order
#pragma unroll
    for (int i = 0; i < 8; ++i) {
      const float S = sz[row0 + ty8 + i];  // wave-uniform, cache-hot
#pragma unroll
      for (int m = 0; m < 4; ++m)
#pragma unroll
        for (int s = 0; s < 4; ++s) {
          const float dist = fmaf(-2.0f, acc[i][m * 4 + s], S);
          const int code = c0 + m * 256 + tx * 4 + s;
          if (dist < best[i]) {  // strict <: earliest index wins
            best[i] = dist;
            bidx[i] = code;
          }
        }
    }
  }

  // full-wave (64 lane) reduce; prefer smaller index on exact ties
#pragma unroll
  for (int i = 0; i < 8; ++i) {
    float bv = best[i];
    int bi = bidx[i];
#pragma unroll
    for (int m = 1; m < 64; m <<= 1) {
      float ov = __shfl_xor(bv, m, 64);
      int oi = __shfl_xor(bi, m, 64);
      if (ov < bv || (ov == bv && oi < bi)) { bv = ov; bi = oi; }
    }
    if (tx == 0) {
      int row = row0 + ty8 + i;
      idx_i[row] = bi;
      idx_f[row] = (float)bi;
    }
  }
}

// ---- gather z_q = emb[idx], partial sums of (z_q - z)^2 ----
__global__ void gather_kernel(const float* __restrict__ z,
                              const float* __restrict__ emb,
                              const int* __restrict__ idx,
                              float* __restrict__ zq,
                              float* __restrict__ partial) {
  const int w = threadIdx.x >> 6;
  const int lane = threadIdx.x & 63;
  const int row = blockIdx.x * 4 + w;
  const int k = idx[row];
  const float4 e = reinterpret_cast<const float4*>(emb)[(size_t)k * (ND / 4) + lane];
  const float4 zv = reinterpret_cast<const float4*>(z)[(size_t)row * (ND / 4) + lane];
  reinterpret_cast<float4*>(zq)[(size_t)row * (ND / 4) + lane] = e;
  const float dx = e.x - zv.x, dy = e.y - zv.y, dz = e.z - zv.z, dw = e.w - zv.w;
  float s = dx * dx + dy * dy + dz * dz + dw * dw;
#pragma unroll
  for (int off = 32; off; off >>= 1) s += __shfl_down(s, off, 64);
  __shared__ float sm[4];
  if (lane == 0) sm[w] = s;
  __syncthreads();
  if (threadIdx.x == 0) partial[blockIdx.x] = sm[0] + sm[1] + sm[2] + sm[3];
}

// ---- deterministic final loss reduction ----
__global__ void loss_kernel(const float* __restrict__ partial, int n,
                            float* __restrict__ out_loss) {
  double s = 0.0;
  for (int i = threadIdx.x; i < n; i += 256) s += (double)partial[i];
  __shared__ double sm[256];
  sm[threadIdx.x] = s;
  __syncthreads();
  for (int st = 128; st; st >>= 1) {
    if (threadIdx.x < st) sm[threadIdx.x] += sm[threadIdx.x + st];
    __syncthreads();
  }
  if (threadIdx.x == 0) {
    float loss = (float)(0.25 * sm[0] / (double)((size_t)NB * ND));
    out_loss[0] = loss;  // vq_loss
    out_loss[1] = loss;  // commitment loss (same forward value)
  }
}

}  // namespace

extern "C" void kernel_launch(void* const* d_in, const int* in_sizes, int n_in,
                              void* d_out, int out_size, void* d_ws, size_t ws_size,
                              hipStream_t stream) {
  const float* z = (const float*)d_in[0];
  const float* emb = (const float*)d_in[1];
  float* out = (float*)d_out;
  float* zq = out;
  float* loss = out + (size_t)NB * ND;
  float* idx_f = out + (size_t)NB * ND + 2;

  int* idx_i = (int*)d_ws;
  float* sz = (float*)((char*)d_ws + (size_t)NB * 4);
  float* partial = (float*)((char*)d_ws + (size_t)NB * 4 * 2);

  sz_kernel<<<NB / 4, 256, 0, stream>>>(z, sz);
  argmin_kernel<<<NB / BM, NT, 0, stream>>>(z, emb, sz, idx_i, idx_f);
  gather_kernel<<<NB / 4, 256, 0, stream>>>(z, emb, idx_i, zq, partial);
  loss_kernel<<<1, 256, 0, stream>>>(partial, NB / 4, loss);
}

// Round 9
// 1713.853 us; speedup vs baseline: 3.1237x; 3.1237x over previous
//
#include <hip/hip_runtime.h>

// VectorQuantizer: B=32768, K=8192, D=256, fp32.
// out layout (flat float): z_q [B*D], vq_loss [1], commit [1], indices-as-float [B]
// ws layout: idx_i int[B] | s_z float[B] | partial float[B/4]
//
// Numerics (verified round 2): ref dist = fl32(S - 2*fl32(dot)), dot = single
// fp32 FMA chain ascending in d per (row,code); frequent exact ties resolved
// by FIRST index. fmaf(-2,acc,S) == fl(S - 2*dot) exactly.
//
// VGPR-cap law (measured r2-r8): cap ~= max(64, 256/ceil(wavesPerBlock*minB/4)):
//   256thr/(256,1)->256 budget (natural 140-152); 512thr/(512,1)->128;
//   (256,2)->128; (512,4)->64. amdgpu_waves_per_eu inert. Occupancy (r7/r8):
//   one block per CU only — 4-wave block = 1 wave/SIMD (12%), 8-wave = 2/SIMD (23%).
//
// Round-9: round-5 geometry (8x8 tile, acc=64) under the 128 cap, 8-wave block:
//   512 threads, tx=tid&63 codes, ty=tid>>6 row-group. BM=64, BN=512, BK=4.
//   LDS: zT 64KB + eT[2][4][512] 16KB = 80KB -> 1 block/CU, 8 waves/CU.
//   Register need ~118 < 128: no spill. eb ping-pong across dd; za broadcast.
//   Per dd per CU: VALU 256cyc vs LDS ~160cyc -> VALU-bound.

namespace {
constexpr int NB = 32768;
constexpr int NK = 8192;
constexpr int ND = 256;
constexpr int BM = 64;    // rows per block
constexpr int BN = 512;   // codes per chunk
constexpr int BK = 4;     // d per stage
constexpr int NT = 512;   // threads per block (8 waves)

// ---- S[row] = ||z_row||^2 ----
__global__ void sz_kernel(const float* __restrict__ z, float* __restrict__ sz) {
  const int row = blockIdx.x * 4 + (threadIdx.x >> 6);
  const int lane = threadIdx.x & 63;
  const float4 v = reinterpret_cast<const float4*>(z)[(size_t)row * (ND / 4) + lane];
  float s = v.x * v.x + v.y * v.y + v.z * v.z + v.w * v.w;
#pragma unroll
  for (int off = 32; off; off >>= 1) s += __shfl_down(s, off, 64);
  if (lane == 0) sz[row] = s;
}

// ---- argmin over codes of fl32(S - 2*fl32(z.e)), first-index tie-break ----
__global__ __launch_bounds__(NT, 1) void argmin_kernel(
    const float* __restrict__ z, const float* __restrict__ emb,
    const float* __restrict__ sz, int* __restrict__ idx_i,
    float* __restrict__ idx_f) {
  __shared__ float zT[ND][BM];       // 64 KB, persistent z^T tile
  __shared__ float eT[2][BK][BN];    // 16 KB, double-buffered e^T chunk

  const int tid = threadIdx.x;
  const int tx = tid & 63;   // code lane (full wave)
  const int ty = tid >> 6;   // wave id = row group (0..7), wave-uniform
  const int ty8 = ty * 8;
  const int row0 = blockIdx.x * BM;

  // stage zT (transpose z[row][d] -> zT[d][row]); coalesced, one-time
  {
    const float4* z4 = reinterpret_cast<const float4*>(z) + (size_t)row0 * (ND / 4);
#pragma unroll
    for (int it = 0; it < 8; ++it) {
      int fi = it * NT + tid;  // float4 index in tile (64 rows * 64 f4/row)
      int r = fi >> 6;
      int dq = fi & 63;
      float4 v = z4[(size_t)r * (ND / 4) + dq];
      zT[dq * 4 + 0][r] = v.x;
      zT[dq * 4 + 1][r] = v.y;
      zT[dq * 4 + 2][r] = v.z;
      zT[dq * 4 + 3][r] = v.w;
    }
  }

  float best[8];
  int bidx[8];
#pragma unroll
  for (int i = 0; i < 8; ++i) { best[i] = 3.4e38f; bidx[i] = 0; }

  const float4* e4 = reinterpret_cast<const float4*>(emb);

  float eb[2][8];
  auto leb = [&](int b, int buf, int dd) {
    const float4 e0 = *reinterpret_cast<const float4*>(&eT[buf][dd][tx * 4]);
    const float4 e1 = *reinterpret_cast<const float4*>(&eT[buf][dd][256 + tx * 4]);
    eb[b][0] = e0.x; eb[b][1] = e0.y; eb[b][2] = e0.z; eb[b][3] = e0.w;
    eb[b][4] = e1.x; eb[b][5] = e1.y; eb[b][6] = e1.z; eb[b][7] = e1.w;
  };

  for (int n = 0; n < NK / BN; ++n) {  // 16 chunks
    const int c0 = n * BN;
    float acc[8][8];
#pragma unroll
    for (int i = 0; i < 8; ++i)
#pragma unroll
      for (int j = 0; j < 8; ++j) acc[i][j] = 0.f;

    // preload dk=0 slice: thread stages code c0+tid (1 float4 = 4 d values)
    float4 p = e4[(size_t)(c0 + tid) * (ND / 4) + 0];

    for (int dk = 0; dk < ND / BK; ++dk) {  // 64 stages
      const int buf = dk & 1;
      // transposed store eT[dd][code]; lane-consecutive -> conflict-free
      eT[buf][0][tid] = p.x;
      eT[buf][1][tid] = p.y;
      eT[buf][2][tid] = p.z;
      eT[buf][3][tid] = p.w;
      if (dk + 1 < ND / BK) {  // prefetch next slice (L2/L3-served)
        p = e4[(size_t)(c0 + tid) * (ND / 4) + dk + 1];
      }
      __syncthreads();  // dbuf: single barrier per stage
      leb(0, buf, 0);
#pragma unroll
      for (int dd = 0; dd < BK; ++dd) {
        const int cur = dd & 1;
        if (dd < BK - 1) leb(cur ^ 1, buf, dd + 1);  // prefetch next dd's eb
        const int d = dk * BK + dd;
        // za: one address per wave (ty uniform) -> broadcast b128 reads
        const float4 a0 = *reinterpret_cast<const float4*>(&zT[d][ty8]);
        const float4 a1 = *reinterpret_cast<const float4*>(&zT[d][ty8 + 4]);
        const float za[8] = {a0.x, a0.y, a0.z, a0.w, a1.x, a1.y, a1.z, a1.w};
        // single fp32 FMA chain per (row, code), ascending d
#pragma unroll
        for (int i = 0; i < 8; ++i)
#pragma unroll
          for (int j = 0; j < 8; ++j)
            acc[i][j] = fmaf(za[i], eb[cur][j], acc[i][j]);
      }
    }

    // running argmin: dist = fl32(S - 2*fl32(dot)); ascending code order
#pragma unroll
    for (int i = 0; i < 8; ++i) {
      const float S = sz[row0 + ty8 + i];  // wave-uniform, cache-hot
#pragma unroll
      for (int m = 0; m < 2; ++m)
#pragma unroll
        for (int s = 0; s < 4; ++s) {
          const float dist = fmaf(-2.0f, acc[i][m * 4 + s], S);
          const int code = c0 + m * 256 + tx * 4 + s;
          if (dist < best[i]) {  // strict <: earliest index wins
            best[i] = dist;
            bidx[i] = code;
          }
        }
    }
  }

  // full-wave (64 lane) reduce; prefer smaller index on exact ties
#pragma unroll
  for (int i = 0; i < 8; ++i) {
    float bv = best[i];
    int bi = bidx[i];
#pragma unroll
    for (int m = 1; m < 64; m <<= 1) {
      float ov = __shfl_xor(bv, m, 64);
      int oi = __shfl_xor(bi, m, 64);
      if (ov < bv || (ov == bv && oi < bi)) { bv = ov; bi = oi; }
    }
    if (tx == 0) {
      int row = row0 + ty8 + i;
      idx_i[row] = bi;
      idx_f[row] = (float)bi;
    }
  }
}

// ---- gather z_q = emb[idx], partial sums of (z_q - z)^2 ----
__global__ void gather_kernel(const float* __restrict__ z,
                              const float* __restrict__ emb,
                              const int* __restrict__ idx,
                              float* __restrict__ zq,
                              float* __restrict__ partial) {
  const int w = threadIdx.x >> 6;
  const int lane = threadIdx.x & 63;
  const int row = blockIdx.x * 4 + w;
  const int k = idx[row];
  const float4 e = reinterpret_cast<const float4*>(emb)[(size_t)k * (ND / 4) + lane];
  const float4 zv = reinterpret_cast<const float4*>(z)[(size_t)row * (ND / 4) + lane];
  reinterpret_cast<float4*>(zq)[(size_t)row * (ND / 4) + lane] = e;
  const float dx = e.x - zv.x, dy = e.y - zv.y, dz = e.z - zv.z, dw = e.w - zv.w;
  float s = dx * dx + dy * dy + dz * dz + dw * dw;
#pragma unroll
  for (int off = 32; off; off >>= 1) s += __shfl_down(s, off, 64);
  __shared__ float sm[4];
  if (lane == 0) sm[w] = s;
  __syncthreads();
  if (threadIdx.x == 0) partial[blockIdx.x] = sm[0] + sm[1] + sm[2] + sm[3];
}

// ---- deterministic final loss reduction ----
__global__ void loss_kernel(const float* __restrict__ partial, int n,
                            float* __restrict__ out_loss) {
  double s = 0.0;
  for (int i = threadIdx.x; i < n; i += 256) s += (double)partial[i];
  __shared__ double sm[256];
  sm[threadIdx.x] = s;
  __syncthreads();
  for (int st = 128; st; st >>= 1) {
    if (threadIdx.x < st) sm[threadIdx.x] += sm[threadIdx.x + st];
    __syncthreads();
  }
  if (threadIdx.x == 0) {
    float loss = (float)(0.25 * sm[0] / (double)((size_t)NB * ND));
    out_loss[0] = loss;  // vq_loss
    out_loss[1] = loss;  // commitment loss (same forward value)
  }
}

}  // namespace

extern "C" void kernel_launch(void* const* d_in, const int* in_sizes, int n_in,
                              void* d_out, int out_size, void* d_ws, size_t ws_size,
                              hipStream_t stream) {
  const float* z = (const float*)d_in[0];
  const float* emb = (const float*)d_in[1];
  float* out = (float*)d_out;
  float* zq = out;
  float* loss = out + (size_t)NB * ND;
  float* idx_f = out + (size_t)NB * ND + 2;

  int* idx_i = (int*)d_ws;
  float* sz = (float*)((char*)d_ws + (size_t)NB * 4);
  float* partial = (float*)((char*)d_ws + (size_t)NB * 4 * 2);

  sz_kernel<<<NB / 4, 256, 0, stream>>>(z, sz);
  argmin_kernel<<<NB / BM, NT, 0, stream>>>(z, emb, sz, idx_i, idx_f);
  gather_kernel<<<NB / 4, 256, 0, stream>>>(z, emb, idx_i, zq, partial);
  loss_kernel<<<1, 256, 0, stream>>>(partial, NB / 4, loss);
}